// Round 4
// baseline (207.463 us; speedup 1.0000x reference)
//
#include <hip/hip_runtime.h>
#include <hip/hip_bf16.h>
#include <math.h>
#include <stdint.h>

#define BDIM 2
#define NDIM 512
#define HID 768
#define BIAF 256
#define CLS 14
#define DD 257   // BIAF+1
#define NPOS 30
#define SDIM 25
#define HSZ 539  // 2*257+25
#define PK 288   // padded contraction length (i and j), 9*32
#define PJ 384   // packW j-rows padding
#define ASTRIDE 296  // A-slab row stride (elems): 16B-slot stride 37 (odd) -> bank-spread

typedef unsigned short ushort_t;
typedef __attribute__((ext_vector_type(8))) short short8;   // 8 bf16
typedef __attribute__((ext_vector_type(4))) float floatx4;  // 4 f32
typedef __attribute__((ext_vector_type(4))) unsigned short ushort4_t;

#define MFMA16(a, b, c) __builtin_amdgcn_mfma_f32_16x16x32_bf16((a), (b), (c), 0, 0, 0)

__device__ inline float bf2f(ushort_t u) {
    union { unsigned int i; float f; } c; c.i = ((unsigned)u) << 16; return c.f;
}
__device__ inline ushort_t f2bf(float f) {
    __hip_bfloat16 h = __float2bfloat16(f);
    return *(ushort_t*)&h;
}

// XCD-aware chunked swizzle (T1, bijective when nwg % 8 == 0).
__device__ inline int xcd_swz(int bid, int nwg) {
    int q = nwg >> 3;
    return (bid & 7) * q + (bid >> 3);
}

// async global->LDS, 16B per lane. LDS dest = wave-uniform base + lane*16.
__device__ inline void glds16(const ushort_t* g, const ushort_t* l) {
    __builtin_amdgcn_global_load_lds(
        (const __attribute__((address_space(1))) unsigned int*)(unsigned long long)(uintptr_t)g,
        (__attribute__((address_space(3))) unsigned int*)(unsigned int)(uintptr_t)l,
        16, 0, 0);
}

// ---------------------------------------------------------------------------
// Staged-tile LDS swizzle (rule #21: linear LDS dest via glds, pre-swizzled
// global source, swizzled read).  Tile = [16 rows][32 cols] bf16 per 1KB seg;
// row-pairs form 128B super-rows of eight 16B slots; slot' = slot ^ (srow&7).
// srow/scol: which global (row, col-quad) lane L fetches; rbase: element
// offset of fragment (l16,quad) inside a seg.
// ---------------------------------------------------------------------------

// ---------------------------------------------------------------------------
// prep_all: fused repack_t (blocks 0..1511) + splits/pads (1512..4327).
// ---------------------------------------------------------------------------
__global__ __launch_bounds__(256) void prep_all(
    const float* __restrict__ biafW, ushort_t* __restrict__ packW,
    const float* __restrict__ x, const float* __restrict__ y,
    const float* __restrict__ m1w, const float* __restrict__ m2w,
    const float* __restrict__ hw,  const float* __restrict__ tw,
    ushort_t* __restrict__ xhi, ushort_t* __restrict__ xlo,
    ushort_t* __restrict__ yhi, ushort_t* __restrict__ ylo,
    ushort_t* __restrict__ whi, ushort_t* __restrict__ wlo,
    ushort_t* __restrict__ h1hi, ushort_t* __restrict__ h1lo,
    ushort_t* __restrict__ t1hi, ushort_t* __restrict__ t1lo)
{
    const int bid = blockIdx.x;
    if (bid < 1512) {
        __shared__ float tile[32][33];
        const int ix = bid % 9;
        const int jy = (bid / 9) % 12;
        const int k  = bid / 108;
        const int i0 = ix * 32, j0 = jy * 32;
        const int r8 = threadIdx.x >> 5;
        const int c  = threadIdx.x & 31;
        #pragma unroll
        for (int rr = 0; rr < 4; ++rr) {
            int r = rr * 8 + r8;
            int gi = i0 + r, gj = j0 + c;
            tile[r][c] = (gi < DD && gj < DD) ? biafW[((size_t)k * DD + gi) * DD + gj] : 0.f;
        }
        __syncthreads();
        #pragma unroll
        for (int rr = 0; rr < 4; ++rr) {
            int jr = rr * 8 + r8;
            packW[((size_t)k * PJ + (j0 + jr)) * PK + i0 + c] = f2bf(tile[c][jr]);
        }
        return;
    }
    int tg = (bid - 1512) * 256 + threadIdx.x;
    if (tg < 196608) {
        int mat = tg / 49152;
        int e0  = (tg % 49152) * 4;
        const float* src = (mat == 0) ? m1w : (mat == 1) ? m2w : (mat == 2) ? hw : tw;
        float4 v = *(const float4*)(src + e0);
        size_t o = (size_t)mat * 196608 + e0;
        ushort4_t h, lo;
        h[0] = f2bf(v.x); lo[0] = f2bf(v.x - bf2f(h[0]));
        h[1] = f2bf(v.y); lo[1] = f2bf(v.y - bf2f(h[1]));
        h[2] = f2bf(v.z); lo[2] = f2bf(v.z - bf2f(h[2]));
        h[3] = f2bf(v.w); lo[3] = f2bf(v.w - bf2f(h[3]));
        *(ushort4_t*)(whi + o) = h;
        *(ushort4_t*)(wlo + o) = lo;
    } else if (tg < 589824) {
        int t = tg - 196608;
        int which = t / 196608;
        int e0 = (t % 196608) * 4;
        const float* src = which ? y : x;
        float4 v = *(const float4*)(src + e0);
        ushort4_t h, lo;
        h[0] = f2bf(v.x); lo[0] = f2bf(v.x - bf2f(h[0]));
        h[1] = f2bf(v.y); lo[1] = f2bf(v.y - bf2f(h[1]));
        h[2] = f2bf(v.z); lo[2] = f2bf(v.z - bf2f(h[2]));
        h[3] = f2bf(v.w); lo[3] = f2bf(v.w - bf2f(h[3]));
        *(ushort4_t*)((which ? yhi : xhi) + e0) = h;
        *(ushort4_t*)((which ? ylo : xlo) + e0) = lo;
    } else {
        int idx = tg - 589824;                 // 0..131071
        int plane = idx >> 15;
        int tok = (idx >> 5) & 1023;
        int c   = 256 + (idx & 31);
        ushort_t* dst = (plane == 0) ? h1hi : (plane == 1) ? h1lo : (plane == 2) ? t1hi : t1lo;
        ushort_t val = (c == 256 && (plane == 0 || plane == 2)) ? (ushort_t)0x3F80 : (ushort_t)0;
        dst[(size_t)tok * PK + c] = val;
    }
}

// ---------------------------------------------------------------------------
// proj_mfma: direct-load MFMA, pre-split operands, 3-term. 1D grid 512,
// XCD-swizzled. wave tile = 16 tokens x 32 features.
// ---------------------------------------------------------------------------
__global__ __launch_bounds__(256) void proj_mfma(
    const ushort_t* __restrict__ xhi, const ushort_t* __restrict__ xlo,
    const ushort_t* __restrict__ yhi, const ushort_t* __restrict__ ylo,
    const ushort_t* __restrict__ whi, const ushort_t* __restrict__ wlo,
    const float* __restrict__ m1b, const float* __restrict__ m2b,
    const float* __restrict__ hb,  const float* __restrict__ tb,
    ushort_t* __restrict__ h1hi, ushort_t* __restrict__ h1lo,
    ushort_t* __restrict__ t1hi, ushort_t* __restrict__ t1lo,
    float* __restrict__ headf, float* __restrict__ tailf)
{
    const int flat = xcd_swz(blockIdx.x, 512);
    const int ft = flat & 7;
    const int mt = (flat >> 3) & 15;
    const int proj = flat >> 7;
    const int wave = threadIdx.x >> 6, L = threadIdx.x & 63;
    const int quad = L >> 4, l16 = L & 15;
    const int tok0 = mt * 64 + wave * 16;
    const int f0 = ft * 32;

    const ushort_t* ahi_p = (proj == 1) ? yhi : xhi;
    const ushort_t* alo_p = (proj == 1) ? ylo : xlo;
    const float* bias = (proj == 0) ? m1b : (proj == 1) ? m2b : (proj == 2) ? hb : tb;

    const size_t aoff = (size_t)(tok0 + l16) * HID + quad * 8;
    const size_t wbase = (size_t)proj * BIAF * HID;
    const size_t b0 = wbase + (size_t)(f0 + l16) * HID + quad * 8;
    const size_t b1 = wbase + (size_t)(f0 + 16 + l16) * HID + quad * 8;

    floatx4 acc0 = {0.f, 0.f, 0.f, 0.f}, acc1 = {0.f, 0.f, 0.f, 0.f};
    #pragma unroll 4
    for (int k0 = 0; k0 < HID; k0 += 32) {
        short8 ah  = *(const short8*)(ahi_p + aoff + k0);
        short8 al  = *(const short8*)(alo_p + aoff + k0);
        short8 bh0 = *(const short8*)(whi + b0 + k0);
        short8 bl0 = *(const short8*)(wlo + b0 + k0);
        short8 bh1 = *(const short8*)(whi + b1 + k0);
        short8 bl1 = *(const short8*)(wlo + b1 + k0);
        acc0 = MFMA16(ah, bh0, acc0);
        acc1 = MFMA16(ah, bh1, acc1);
        acc0 = MFMA16(al, bh0, acc0);
        acc1 = MFMA16(al, bh1, acc1);
        acc0 = MFMA16(ah, bl0, acc0);
        acc1 = MFMA16(ah, bl1, acc1);
    }

    #pragma unroll
    for (int nf = 0; nf < 2; ++nf) {
        floatx4 a = nf ? acc1 : acc0;
        int feat = f0 + nf * 16 + l16;
        float bv = bias[feat];
        #pragma unroll
        for (int r = 0; r < 4; ++r) {
            int tok = tok0 + quad * 4 + r;
            float v = a[r] + bv;
            if (proj <= 1) {
                float g = 0.5f * v * (1.0f + erff(v * 0.70710678118654752f));
                ushort_t h = f2bf(g);
                ushort_t lo = f2bf(g - bf2f(h));
                if (proj == 0) { h1hi[(size_t)tok * PK + feat] = h; h1lo[(size_t)tok * PK + feat] = lo; }
                else           { t1hi[(size_t)tok * PK + feat] = h; t1lo[(size_t)tok * PK + feat] = lo; }
            } else {
                float lv = (v >= 0.f) ? v : 0.01f * v;
                if (proj == 2) headf[(size_t)tok * 256 + feat] = lv;
                else           tailf[(size_t)tok * 256 + feat] = lv;
            }
        }
    }
}

// ---------------------------------------------------------------------------
// hk_tk_sk: blocks 0..127: hk/tk; 128..129: sk.
// ---------------------------------------------------------------------------
__global__ __launch_bounds__(256) void hk_tk_sk(
    const float* __restrict__ headf, const float* __restrict__ tailf,
    const float* __restrict__ W, const float* __restrict__ semb,
    float* __restrict__ hk, float* __restrict__ tk, float* __restrict__ skp)
{
    if (blockIdx.x >= 128) {
        int idx = (blockIdx.x - 128) * 256 + threadIdx.x;
        if (idx < CLS * NPOS) {
            int k = idx / NPOS, d = idx % NPOS;
            float acc = 0.f;
            for (int h = 0; h < SDIM; ++h)
                acc += semb[d*SDIM + h] * W[k*HSZ + 2*DD + h];
            skp[idx] = acc;
        }
        return;
    }
    int p = blockIdx.x * 256 + threadIdx.x;
    int which = p >> 14;
    int idx = p & 16383;
    int tok = idx >> 4;
    int k = idx & 15;
    if (k >= CLS) return;
    const float* row = (which ? tailf : headf) + (size_t)tok * 256;
    const float* wr = W + (size_t)k * HSZ + (which ? DD : 0);
    float acc = 0.f;
    for (int f4 = 0; f4 < 64; ++f4) {
        float4 rv = *(const float4*)(row + f4 * 4);
        acc += rv.x * wr[f4*4] + rv.y * wr[f4*4+1] + rv.z * wr[f4*4+2] + rv.w * wr[f4*4+3];
    }
    acc += wr[256];
    float* dst = which ? tk : hk;
    dst[(size_t)(tok >> 9) * CLS * NDIM + (size_t)k * NDIM + (tok & 511)] = acc;
}

// ---------------------------------------------------------------------------
// biaf_fused: mb+mo in one kernel; A-slab lives in LDS (no Abuf round-trip).
// grid = 28 bk x 16 mt = 448 blocks (bk-major flat, XCD-swizzled), 256 thr.
// Phase A: A[32 x 288] = sum_i h1[b, m-tile, i] * packW[k, j, i]  (hi+lo h1)
//   waves: (mi = w>>1: 16-row m-frag, jh = w&1: 9 j-frags of 16).
//   identical MFMA order to old mb_tile -> f2bf(acc) bit-identical.
// Phase B: out[32 x 512] = A . t1^T (+ hk + tk + sk), n-tiles of 128,
//   double-buffered t1 staging, identical order/epilogue to old mo_tile.
// LDS: stage 32KB (A-phase 22KB | B-phase 2x16KB) + Aslab 18.5KB -> 3 blk/CU.
// ---------------------------------------------------------------------------
__global__ __launch_bounds__(256) void biaf_fused(
    const ushort_t* __restrict__ h1hi, const ushort_t* __restrict__ h1lo,
    const ushort_t* __restrict__ packW,
    const ushort_t* __restrict__ t1hi, const ushort_t* __restrict__ t1lo,
    const float* __restrict__ hk, const float* __restrict__ tk,
    const float* __restrict__ sk,
    float* __restrict__ out)
{
    __shared__ __align__(16) ushort_t stage[16384];          // 32 KB
    __shared__ __align__(16) ushort_t Aslab[32 * ASTRIDE];   // 18.5 KB
    __shared__ float skr[NPOS];

    const int flat = xcd_swz(blockIdx.x, 448);
    const int mt = flat & 15, bk = flat >> 4;     // bk-major chunks
    const int b = bk / CLS, k = bk % CLS;
    const int tid = threadIdx.x;
    if (tid < NPOS) skr[tid] = sk[k * NPOS + tid];
    const int wave = tid >> 6, L = tid & 63;
    const int quad = L >> 4, l16 = L & 15;
    const int sr = L >> 3, u = (L & 7) ^ sr;
    const int srow = 2 * sr + (u >> 2);
    const int scol = (u & 3) * 8;
    const int rbase = (l16 >> 1) * 64 + (((((l16 & 1) << 2) | quad) ^ (l16 >> 1)) * 8);
    const int m0 = mt * 32;

    const ushort_t* gAh = h1hi + (size_t)(b * NDIM + m0) * PK;
    const ushort_t* gAl = h1lo + (size_t)(b * NDIM + m0) * PK;
    const ushort_t* gB  = packW + (size_t)k * PJ * PK;

    // ---------------- phase A ----------------
    const int mi = wave >> 1, jh = wave & 1;
    floatx4 accA[9];
    #pragma unroll
    for (int t = 0; t < 9; ++t)
        #pragma unroll
        for (int r = 0; r < 4; ++r) accA[t][r] = 0.f;

    for (int i0 = 0; i0 < PK; i0 += 32) {
        // 22 x 1KB segs: 2 h1hi, 2 h1lo, 18 packW (j rows 0..287)
        for (int s = wave; s < 22; s += 4) {
            const ushort_t* g; const ushort_t* l;
            if (s < 2)      { l = stage + s * 512;  g = gAh + (size_t)(s * 16 + srow) * PK + i0 + scol; }
            else if (s < 4) { l = stage + s * 512;  g = gAl + (size_t)((s - 2) * 16 + srow) * PK + i0 + scol; }
            else            { l = stage + s * 512;  g = gB  + (size_t)((s - 4) * 16 + srow) * PK + i0 + scol; }
            glds16(g, l);
        }
        __syncthreads();
        short8 ah = *(const short8*)(stage + mi * 512 + rbase);
        short8 al = *(const short8*)(stage + 1024 + mi * 512 + rbase);
        #pragma unroll
        for (int t = 0; t < 9; ++t) {
            short8 bt = *(const short8*)(stage + 2048 + (jh * 9 + t) * 512 + rbase);
            accA[t] = MFMA16(ah, bt, accA[t]);
            accA[t] = MFMA16(al, bt, accA[t]);
        }
        __syncthreads();
    }

    // write A-slab (bf16, same rounding as old Abuf)
    #pragma unroll
    for (int t = 0; t < 9; ++t) {
        int jb = (jh * 9 + t) * 16 + l16;
        #pragma unroll
        for (int r = 0; r < 4; ++r) {
            int row = mi * 16 + quad * 4 + r;
            Aslab[row * ASTRIDE + jb] = f2bf(accA[t][r]);
        }
    }
    __syncthreads();

    // ---------------- phase B ----------------
    const int mi2 = wave >> 1, nh = wave & 1;
    const ushort_t* gTh = t1hi + (size_t)(b * NDIM) * PK;
    const ushort_t* gTl = t1lo + (size_t)(b * NDIM) * PK;

    auto stageB = [&](int bo, int nt, int js) {
        // 16 x 1KB segs: 8 t1hi rows [nt*128, +128), 8 t1lo
        for (int s = wave; s < 16; s += 4) {
            const ushort_t* g; const ushort_t* l;
            if (s < 8) { l = stage + bo * 8192 + s * 512;
                         g = gTh + (size_t)(nt * 128 + s * 16 + srow) * PK + js * 32 + scol; }
            else       { l = stage + bo * 8192 + 4096 + (s - 8) * 512;
                         g = gTl + (size_t)(nt * 128 + (s - 8) * 16 + srow) * PK + js * 32 + scol; }
            glds16(g, l);
        }
    };

    stageB(0, 0, 0);
    __syncthreads();
    int cur = 0;
    const size_t obase = (size_t)bk * NDIM;

    for (int nt = 0; nt < 4; ++nt) {
        floatx4 accB[4];
        #pragma unroll
        for (int nf = 0; nf < 4; ++nf)
            #pragma unroll
            for (int r = 0; r < 4; ++r) accB[nf][r] = 0.f;

        for (int js = 0; js < 9; ++js) {
            int step = nt * 9 + js;
            if (step < 35) { int ns = step + 1; stageB(cur ^ 1, ns / 9, ns % 9); }
            short8 a = *(const short8*)(Aslab + (mi2 * 16 + l16) * ASTRIDE + js * 32 + quad * 8);
            #pragma unroll
            for (int nf = 0; nf < 4; ++nf) {
                short8 bh = *(const short8*)(stage + cur * 8192 + (nh * 4 + nf) * 512 + rbase);
                short8 bl = *(const short8*)(stage + cur * 8192 + 4096 + (nh * 4 + nf) * 512 + rbase);
                accB[nf] = MFMA16(a, bh, accB[nf]);
                accB[nf] = MFMA16(a, bl, accB[nf]);
            }
            __syncthreads();
            cur ^= 1;
        }

        // epilogue for this n-tile (identical math to old mo_tile)
        int n0 = nt * 128;
        #pragma unroll
        for (int r = 0; r < 4; ++r) {
            int row = m0 + mi2 * 16 + quad * 4 + r;
            float hv = hk[obase + row];
            #pragma unroll
            for (int nf = 0; nf < 4; ++nf) {
                int col = n0 + nh * 64 + nf * 16 + l16;
                int d = col - row; d = d < -15 ? -15 : (d > 14 ? 14 : d); d += 15;
                out[(obase + row) * NDIM + col] = accB[nf][r] + hv + tk[obase + col] + skr[d];
            }
        }
    }
}

// ---------------------------------------------------------------------------
extern "C" void kernel_launch(void* const* d_in, const int* in_sizes, int n_in,
                              void* d_out, int out_size, void* d_ws, size_t ws_size,
                              hipStream_t stream) {
    const float* x    = (const float*)d_in[0];
    const float* y    = (const float*)d_in[1];
    // d_in[2] = z : unused
    const float* m1w  = (const float*)d_in[3];
    const float* m1b  = (const float*)d_in[4];
    const float* m2w  = (const float*)d_in[5];
    const float* m2b  = (const float*)d_in[6];
    const float* hw   = (const float*)d_in[7];
    const float* hb   = (const float*)d_in[8];
    const float* tw   = (const float*)d_in[9];
    const float* tb   = (const float*)d_in[10];
    const float* biafW= (const float*)d_in[11];
    const float* W    = (const float*)d_in[12];
    const float* semb = (const float*)d_in[13];

    char* p = (char*)d_ws;
    float* hk   = (float*)p;                    p += 57344;
    float* tk   = (float*)p;                    p += 57344;
    float* skp  = (float*)p;                    p += 2048;
    float* headf= (float*)p;                    p += 1048576;
    float* tailf= (float*)p;                    p += 1048576;
    ushort_t* h1hi = (ushort_t*)p;              p += 589824;
    ushort_t* h1lo = (ushort_t*)p;              p += 589824;
    ushort_t* t1hi = (ushort_t*)p;              p += 589824;
    ushort_t* t1lo = (ushort_t*)p;              p += 589824;
    ushort_t* packW= (ushort_t*)p;              p += 3096576;  // 14*384*288*2
    ushort_t* whi  = (ushort_t*)p;              p += 1572864;  // 4*256*768*2
    ushort_t* wlo  = (ushort_t*)p;              p += 1572864;
    ushort_t* xhi  = (ushort_t*)p;              p += 1572864;  // 1024*768*2
    ushort_t* xlo  = (ushort_t*)p;              p += 1572864;
    ushort_t* yhi  = (ushort_t*)p;              p += 1572864;
    ushort_t* ylo  = (ushort_t*)p;              p += 1572864;

    prep_all<<<4328, 256, 0, stream>>>(biafW, packW, x, y, m1w, m2w, hw, tw,
                                       xhi, xlo, yhi, ylo, whi, wlo,
                                       h1hi, h1lo, t1hi, t1lo);
    proj_mfma<<<512, 256, 0, stream>>>(xhi, xlo, yhi, ylo, whi, wlo,
                                       m1b, m2b, hb, tb,
                                       h1hi, h1lo, t1hi, t1lo, headf, tailf);
    hk_tk_sk<<<130, 256, 0, stream>>>(headf, tailf, W, semb, hk, tk, skp);
    biaf_fused<<<448, 256, 0, stream>>>(h1hi, h1lo, packW, t1hi, t1lo,
                                        hk, tk, skp, (float*)d_out);
}